// Round 1
// baseline (694.058 us; speedup 1.0000x reference)
//
#include <hip/hip_runtime.h>

// Problem constants
#define Bb 16
#define Nn_ 576
#define Cc 1024
#define Hh 16
#define HD 64
#define HID 4096
#define AVAIL 832   // CUR(256) + N(576)
#define ROWS (Bb*Nn_)  // 9216

typedef __bf16 bf16x8 __attribute__((ext_vector_type(8)));
typedef float f32x4 __attribute__((ext_vector_type(4)));

__device__ __forceinline__ unsigned short f2bf(float f) {
  unsigned u = __float_as_uint(f);
  u += 0x7FFF + ((u >> 16) & 1);
  return (unsigned short)(u >> 16);
}

__device__ __forceinline__ void glds16(const void* g, void* l) {
  __builtin_amdgcn_global_load_lds(
      (const __attribute__((address_space(1))) void*)g,
      (__attribute__((address_space(3))) void*)l, 16, 0, 0);
}

// ---------------- weight convert + transpose: in [K][N] f32 -> out [N][K] bf16
__global__ void wtrans_k(const float* __restrict__ in, unsigned short* __restrict__ out,
                         int K, int N) {
  __shared__ float tile[32][33];
  int k0 = blockIdx.x * 32, n0 = blockIdx.y * 32;
  int tx = threadIdx.x, ty = threadIdx.y;  // 32 x 8
#pragma unroll
  for (int i = 0; i < 4; i++)
    tile[ty + i * 8][tx] = in[(size_t)(k0 + ty + i * 8) * N + n0 + tx];
  __syncthreads();
#pragma unroll
  for (int i = 0; i < 4; i++)
    out[(size_t)(n0 + ty + i * 8) * K + k0 + tx] = f2bf(tile[tx][ty + i * 8]);
}

// ---------------- LayerNorm f32 -> bf16, one block per row of 1024
__global__ void ln_k(const float* __restrict__ x, const float* __restrict__ w,
                     const float* __restrict__ bi, unsigned short* __restrict__ out) {
  int row = blockIdx.x;
  int t = threadIdx.x;
  float4 v = ((const float4*)(x + (size_t)row * Cc))[t];
  float s = v.x + v.y + v.z + v.w;
  float s2 = v.x * v.x + v.y * v.y + v.z * v.z + v.w * v.w;
#pragma unroll
  for (int off = 1; off < 64; off <<= 1) { s += __shfl_xor(s, off); s2 += __shfl_xor(s2, off); }
  __shared__ float red[8];
  int wid = t >> 6, lane = t & 63;
  if (lane == 0) { red[wid] = s; red[4 + wid] = s2; }
  __syncthreads();
  s = red[0] + red[1] + red[2] + red[3];
  s2 = red[4] + red[5] + red[6] + red[7];
  float mean = s * (1.0f / Cc);
  float var = s2 * (1.0f / Cc) - mean * mean;
  float rstd = rsqrtf(var + 1e-5f);
  float4 wv = ((const float4*)w)[t];
  float4 bv = ((const float4*)bi)[t];
  ushort4 ov;
  ov.x = f2bf((v.x - mean) * rstd * wv.x + bv.x);
  ov.y = f2bf((v.y - mean) * rstd * wv.y + bv.y);
  ov.z = f2bf((v.z - mean) * rstd * wv.z + bv.z);
  ov.w = f2bf((v.w - mean) * rstd * wv.w + bv.w);
  *(ushort4*)(out + (size_t)row * Cc + t * 4) = ov;
}

// ---------------- GEMM: C[M][N] = A[M][K](bf16) @ Bt[N][K]^T (bf16) + bias
// EPI: 0 = bf16 out; 1 = gelu -> bf16 out; 2 = f32 out with residual add
template <int EPI>
__global__ __launch_bounds__(256) void gemm_k(
    const unsigned short* __restrict__ A, const unsigned short* __restrict__ Bt,
    const float* __restrict__ bias, const float* __restrict__ resid,
    void* __restrict__ outv, int M, int N, int K) {
  __shared__ __attribute__((aligned(16))) unsigned short lA[128 * 32];
  __shared__ __attribute__((aligned(16))) unsigned short lB[128 * 32];
  const int tid = threadIdx.x;
  const int lane = tid & 63;
  const int wr = (tid >> 6) >> 1, wc = (tid >> 6) & 1;
  const int m0 = blockIdx.x * 128, n0 = blockIdx.y * 128;

  f32x4 acc[4][4] = {};

  const int arow = tid >> 2;           // 0..63
  const int acolb = (tid & 3) << 4;    // byte offset in 64B row
  const char* Ab = (const char*)A;
  const char* Bbp = (const char*)Bt;

  for (int kt = 0; kt < K; kt += 32) {
    __syncthreads();
    glds16(Ab + ((size_t)(m0 + arow) * K + kt) * 2 + acolb, (char*)lA + tid * 16);
    glds16(Ab + ((size_t)(m0 + arow + 64) * K + kt) * 2 + acolb, (char*)lA + 4096 + tid * 16);
    glds16(Bbp + ((size_t)(n0 + arow) * K + kt) * 2 + acolb, (char*)lB + tid * 16);
    glds16(Bbp + ((size_t)(n0 + arow + 64) * K + kt) * 2 + acolb, (char*)lB + 4096 + tid * 16);
    asm volatile("s_waitcnt vmcnt(0)" ::: "memory");
    __syncthreads();

    bf16x8 af[4], bfv[4];
#pragma unroll
    for (int mi = 0; mi < 4; mi++)
      af[mi] = *(const bf16x8*)&lA[(wr * 64 + mi * 16 + (lane & 15)) * 32 + (lane >> 4) * 8];
#pragma unroll
    for (int ni = 0; ni < 4; ni++)
      bfv[ni] = *(const bf16x8*)&lB[(wc * 64 + ni * 16 + (lane & 15)) * 32 + (lane >> 4) * 8];
#pragma unroll
    for (int mi = 0; mi < 4; mi++)
#pragma unroll
      for (int ni = 0; ni < 4; ni++)
        acc[mi][ni] = __builtin_amdgcn_mfma_f32_16x16x32_bf16(af[mi], bfv[ni], acc[mi][ni], 0, 0, 0);
  }

#pragma unroll
  for (int mi = 0; mi < 4; mi++) {
#pragma unroll
    for (int ni = 0; ni < 4; ni++) {
      int col = n0 + wc * 64 + ni * 16 + (lane & 15);
      int rbase = m0 + wr * 64 + mi * 16 + (lane >> 4) * 4;
      float bv = bias[col];
#pragma unroll
      for (int j = 0; j < 4; j++) {
        size_t idx = (size_t)(rbase + j) * N + col;
        float v = acc[mi][ni][j] + bv;
        if (EPI == 1) v = 0.5f * v * (1.0f + erff(v * 0.70710678118f));
        if (EPI == 2)
          ((float*)outv)[idx] = v + resid[idx];
        else
          ((unsigned short*)outv)[idx] = f2bf(v);
      }
    }
  }
}

// ---------------- gather K: Kg[bh][p][d] (bf16) from qkv + cache_k
__global__ void gatherk_k(const unsigned short* __restrict__ qkv,
                          const float* __restrict__ cache_k,
                          unsigned short* __restrict__ Kg) {
  int bh = blockIdx.y, b = bh >> 4, h = bh & 15;
  int p = blockIdx.x * 4 + (threadIdx.x >> 6);
  int d = threadIdx.x & 63;
  unsigned short val;
  if (p < 64)
    val = qkv[((size_t)(b * Nn_ + p)) * 3072 + 1024 + h * 64 + d];
  else if (p < 320)
    val = f2bf(cache_k[(((size_t)b * Hh + h) * 1024 + p) * 64 + d]);
  else
    val = qkv[((size_t)(b * Nn_ + p - 256)) * 3072 + 1024 + h * 64 + d];
  Kg[(((size_t)bh) * AVAIL + p) * 64 + d] = val;
}

// ---------------- gather V transposed: Vt[bh][d][p] (bf16)
__global__ void gathervt_k(const unsigned short* __restrict__ qkv,
                           const float* __restrict__ cache_v,
                           unsigned short* __restrict__ Vt) {
  __shared__ float tile[32][33];
  int bh = blockIdx.z, b = bh >> 4, h = bh & 15;
  int p0 = blockIdx.x * 32, d0 = blockIdx.y * 32;
  int tx = threadIdx.x, ty = threadIdx.y;  // 32 x 8
#pragma unroll
  for (int i = 0; i < 4; i++) {
    int p = p0 + ty + i * 8, d = d0 + tx;
    float v;
    if (p < 64)
      v = __uint_as_float((unsigned)qkv[((size_t)(b * Nn_ + p)) * 3072 + 2048 + h * 64 + d] << 16);
    else if (p < 320)
      v = cache_v[(((size_t)b * Hh + h) * 1024 + p) * 64 + d];
    else
      v = __uint_as_float((unsigned)qkv[((size_t)(b * Nn_ + p - 256)) * 3072 + 2048 + h * 64 + d] << 16);
    tile[ty + i * 8][tx] = v;
  }
  __syncthreads();
#pragma unroll
  for (int i = 0; i < 4; i++)
    Vt[(((size_t)bh) * 64 + d0 + ty + i * 8) * AVAIL + p0 + tx] = f2bf(tile[tx][ty + i * 8]);
}

// ---------------- flash attention: block = (qtile, bh); 4 waves x 16 q-rows
__global__ __launch_bounds__(256) void attn_k(
    const unsigned short* __restrict__ qkv, const unsigned short* __restrict__ Kg,
    const unsigned short* __restrict__ Vt, unsigned short* __restrict__ o) {
  __shared__ __attribute__((aligned(16))) unsigned short Qs[64 * 64];
  __shared__ __attribute__((aligned(16))) unsigned short Ks[64 * 64];
  __shared__ __attribute__((aligned(16))) unsigned short Vs[64 * 64];
  __shared__ __attribute__((aligned(16))) unsigned short Ps[4][16 * 64];

  const int tid = threadIdx.x;
  const int lane = tid & 63;
  const int w = tid >> 6;
  const int qt = blockIdx.x;
  const int bh = blockIdx.y, b = bh >> 4, h = bh & 15;
  const float scale = 0.125f;

  // stage Q tile [64 q][64 d] (rows of 128B from qkv, col h*64)
  {
    int r = tid >> 3;
    int cb = (tid & 7) << 4;
    const char* qb = (const char*)qkv;
    glds16(qb + ((size_t)(b * Nn_ + qt * 64 + r) * 3072 + h * 64) * 2 + cb, (char*)Qs + tid * 16);
    glds16(qb + ((size_t)(b * Nn_ + qt * 64 + 32 + r) * 3072 + h * 64) * 2 + cb,
           (char*)Qs + 4096 + tid * 16);
  }

  float m_run[4], l_run[4];
  f32x4 oacc[4] = {};
#pragma unroll
  for (int j = 0; j < 4; j++) { m_run[j] = -1e30f; l_run[j] = 0.f; }

  const char* kbase = (const char*)(Kg + (size_t)bh * AVAIL * 64);
  const char* vbase = (const char*)(Vt + (size_t)bh * 64 * AVAIL);

  for (int c = 0; c < 13; c++) {
    __syncthreads();
    // K chunk: contiguous 8KB
    glds16(kbase + (size_t)c * 8192 + tid * 16, (char*)Ks + tid * 16);
    glds16(kbase + (size_t)c * 8192 + 4096 + tid * 16, (char*)Ks + 4096 + tid * 16);
    // V^T chunk: 64 rows of 128B, row stride AVAIL*2
    {
      int r = tid >> 3;
      int cb = (tid & 7) << 4;
      glds16(vbase + (size_t)r * (AVAIL * 2) + c * 128 + cb, (char*)Vs + tid * 16);
      glds16(vbase + (size_t)(r + 32) * (AVAIL * 2) + c * 128 + cb, (char*)Vs + 4096 + tid * 16);
    }
    asm volatile("s_waitcnt vmcnt(0)" ::: "memory");
    __syncthreads();

    // S = Q @ K^T  (16 q-rows per wave, 64 keys)
    bf16x8 qf[2];
#pragma unroll
    for (int t = 0; t < 2; t++)
      qf[t] = *(const bf16x8*)&Qs[(w * 16 + (lane & 15)) * 64 + t * 32 + (lane >> 4) * 8];
    f32x4 s[4] = {};
#pragma unroll
    for (int nt = 0; nt < 4; nt++) {
#pragma unroll
      for (int t = 0; t < 2; t++) {
        bf16x8 kf = *(const bf16x8*)&Ks[(nt * 16 + (lane & 15)) * 64 + t * 32 + (lane >> 4) * 8];
        s[nt] = __builtin_amdgcn_mfma_f32_16x16x32_bf16(qf[t], kf, s[nt], 0, 0, 0);
      }
    }

    // online softmax (row r = (lane>>4)*4+j lives in 16 contiguous lanes)
    float p[4][4];
#pragma unroll
    for (int j = 0; j < 4; j++) {
      float mx = fmaxf(fmaxf(s[0][j], s[1][j]), fmaxf(s[2][j], s[3][j])) * scale;
#pragma unroll
      for (int off = 1; off < 16; off <<= 1) mx = fmaxf(mx, __shfl_xor(mx, off));
      float m_new = fmaxf(m_run[j], mx);
      float alpha = __expf(m_run[j] - m_new);
      float sum = 0.f;
#pragma unroll
      for (int nt = 0; nt < 4; nt++) {
        p[nt][j] = __expf(s[nt][j] * scale - m_new);
        sum += p[nt][j];
      }
#pragma unroll
      for (int off = 1; off < 16; off <<= 1) sum += __shfl_xor(sum, off);
      l_run[j] = l_run[j] * alpha + sum;
      m_run[j] = m_new;
#pragma unroll
      for (int nt2 = 0; nt2 < 4; nt2++) oacc[nt2][j] *= alpha;
    }

    // P -> LDS (re-fragment), then O += P @ V
#pragma unroll
    for (int nt = 0; nt < 4; nt++)
#pragma unroll
      for (int j = 0; j < 4; j++)
        Ps[w][((lane >> 4) * 4 + j) * 64 + nt * 16 + (lane & 15)] = f2bf(p[nt][j]);

    bf16x8 pa[2];
#pragma unroll
    for (int t = 0; t < 2; t++)
      pa[t] = *(const bf16x8*)&Ps[w][(lane & 15) * 64 + t * 32 + (lane >> 4) * 8];
#pragma unroll
    for (int nt2 = 0; nt2 < 4; nt2++) {
#pragma unroll
      for (int t = 0; t < 2; t++) {
        bf16x8 vf = *(const bf16x8*)&Vs[(nt2 * 16 + (lane & 15)) * 64 + t * 32 + (lane >> 4) * 8];
        oacc[nt2] = __builtin_amdgcn_mfma_f32_16x16x32_bf16(pa[t], vf, oacc[nt2], 0, 0, 0);
      }
    }
  }

  // normalize + write o in [B, N, H*64] layout (== transpose(0,2,1,3).reshape)
#pragma unroll
  for (int nt2 = 0; nt2 < 4; nt2++) {
#pragma unroll
    for (int j = 0; j < 4; j++) {
      int q = qt * 64 + w * 16 + (lane >> 4) * 4 + j;
      float v = oacc[nt2][j] / l_run[j];
      o[((size_t)(b * Nn_ + q)) * Cc + h * 64 + nt2 * 16 + (lane & 15)] = f2bf(v);
    }
  }
}

extern "C" void kernel_launch(void* const* d_in, const int* in_sizes, int n_in,
                              void* d_out, int out_size, void* d_ws, size_t ws_size,
                              hipStream_t stream) {
  const float* x = (const float*)d_in[0];
  const float* cache_k = (const float*)d_in[1];
  const float* cache_v = (const float*)d_in[2];
  const float* qkv_w = (const float*)d_in[3];
  const float* qkv_b = (const float*)d_in[4];
  const float* proj_w = (const float*)d_in[5];
  const float* proj_b = (const float*)d_in[6];
  const float* n1w = (const float*)d_in[7];
  const float* n1b = (const float*)d_in[8];
  const float* n2w = (const float*)d_in[9];
  const float* n2b = (const float*)d_in[10];
  const float* fc1w = (const float*)d_in[11];
  const float* fc1b = (const float*)d_in[12];
  const float* fc2w = (const float*)d_in[13];
  const float* fc2b = (const float*)d_in[14];

  char* ws = (char*)d_ws;
  // workspace layout (bytes)
  unsigned short* wq_t = (unsigned short*)(ws + 0);          //  6291456  [3072][1024]
  unsigned short* wp_t = (unsigned short*)(ws + 6291456);    //  2097152  [1024][1024]
  unsigned short* w1_t = (unsigned short*)(ws + 8388608);    //  8388608  [4096][1024]
  unsigned short* w2_t = (unsigned short*)(ws + 16777216);   //  8388608  [1024][4096]
  float* x2           = (float*)(ws + 25165824);             // 37748736  [9216][1024] f32
  unsigned short* obuf = (unsigned short*)(ws + 62914560);   // 18874368  [9216][1024]
  unsigned short* hbuf = (unsigned short*)(ws + 81788928);   // 18874368  [9216][1024]
  unsigned short* vt   = (unsigned short*)(ws + 100663296);  // 27262976  [256][64][832]
  unsigned short* qkvb = (unsigned short*)(ws + 127926272);  // 56623104  [9216][3072]
  unsigned short* kg   = (unsigned short*)(ws + 184549376);  // 27262976  [256][832][64]
  unsigned short* midb = qkvb;  // fc1 out [9216][4096] = 75497472 <= qkv+kg region (83886080)

  dim3 b328(32, 8);
  wtrans_k<<<dim3(32, 96), b328, 0, stream>>>(qkv_w, wq_t, 1024, 3072);
  wtrans_k<<<dim3(32, 32), b328, 0, stream>>>(proj_w, wp_t, 1024, 1024);
  wtrans_k<<<dim3(32, 128), b328, 0, stream>>>(fc1w, w1_t, 1024, 4096);
  wtrans_k<<<dim3(128, 32), b328, 0, stream>>>(fc2w, w2_t, 4096, 1024);

  ln_k<<<ROWS, 256, 0, stream>>>(x, n1w, n1b, hbuf);
  gemm_k<0><<<dim3(72, 24), 256, 0, stream>>>(hbuf, wq_t, qkv_b, nullptr, qkvb, ROWS, 3072, 1024);

  gatherk_k<<<dim3(208, 256), 256, 0, stream>>>(qkvb, cache_k, kg);
  gathervt_k<<<dim3(26, 2, 256), b328, 0, stream>>>(qkvb, cache_v, vt);
  attn_k<<<dim3(9, 256), 256, 0, stream>>>(qkvb, kg, vt, obuf);

  gemm_k<2><<<dim3(72, 8), 256, 0, stream>>>(obuf, wp_t, proj_b, x, x2, ROWS, 1024, 1024);
  ln_k<<<ROWS, 256, 0, stream>>>(x2, n2w, n2b, hbuf);
  gemm_k<1><<<dim3(72, 32), 256, 0, stream>>>(hbuf, w1_t, fc1b, nullptr, midb, ROWS, 4096, 1024);
  gemm_k<2><<<dim3(72, 8), 256, 0, stream>>>(midb, w2_t, fc2b, x2, (float*)d_out, ROWS, 1024, 4096);
}